// Round 7
// baseline (198.806 us; speedup 1.0000x reference)
//
#include <hip/hip_runtime.h>
#include <math.h>

#define N 4096
#define NB 128         // bands per column
#define BANDSZ 32      // rows per band
#define MAXDEG 128
#define NEG_SLOPE 0.2f
#define LN_EPS 1e-5f

__device__ __forceinline__ float wave_reduce_sum(float v) {
    #pragma unroll
    for (int m = 32; m >= 1; m >>= 1) v += __shfl_xor(v, m, 64);
    return v;
}
__device__ __forceinline__ float wave_reduce_max(float v) {
    #pragma unroll
    for (int m = 32; m >= 1; m >>= 1) v = fmaxf(v, __shfl_xor(v, m, 64));
    return v;
}

// row-vector (lane=col) times 64x64 row-major W via shfl broadcast.
__device__ __forceinline__ float transform_row(float hv, const float* __restrict__ W,
                                               int lane) {
    float tr = 0.f;
    #pragma unroll
    for (int k = 0; k < 64; ++k)
        tr += __shfl(hv, k, 64) * W[k * 64 + lane];
    return tr;
}

// Partial gather for the 4-wave-per-row split: this wave sums neighbor
// slots [lo, hi). Softmax m/Z computed redundantly+identically in all
// four waves of a row (same inputs, deterministic ops) — only the partial
// acc needs cross-wave combination (via LDS).
__device__ __forceinline__ float agg_part(int j0, int j1, int deg, float sd,
        const float* __restrict__ ssin, const float* __restrict__ hwin,
        int lane, int lo, int hi, float* Zout) {
    float e0 = -1e30f, e1 = -1e30f;
    if (lane < deg)      { float v = ssin[j0] + sd; e0 = v > 0.f ? v : NEG_SLOPE * v; }
    if (lane + 64 < deg) { float v = ssin[j1] + sd; e1 = v > 0.f ? v : NEG_SLOPE * v; }
    float m = wave_reduce_max(fmaxf(e0, e1));
    float p0 = (lane < deg)      ? expf(e0 - m) : 0.f;
    float p1 = (lane + 64 < deg) ? expf(e1 - m) : 0.f;
    *Zout = wave_reduce_sum(p0 + p1);
    float acc = 0.f;
    int hi0 = min(hi, 64);
    #pragma unroll 8
    for (int n = lo; n < hi0; ++n) {          // slots below 64
        int   jj = __shfl(j0, n, 64);
        float p  = __shfl(p0, n, 64);
        acc += p * hwin[jj * 64 + lane];
    }
    #pragma unroll 2
    for (int n = (lo > 64 ? lo : 64); n < hi; ++n) {   // slots >= 64 (rare)
        int   jj = __shfl(j1, n - 64, 64);
        float p  = __shfl(p1, n - 64, 64);
        acc += p * hwin[jj * 64 + lane];
    }
    return acc;
}

// ---- dispatch 1: BITMASK neighbor build (transposed bmT[col][band]) +
// emb MLP + layer-0 transform. Verified structure (R5/R6, 186 µs).
__global__ void __launch_bounds__(256) prep_kernel(
        const float4* __restrict__ adj4, const int* __restrict__ timestep,
        const float* __restrict__ arr, const float* __restrict__ dep,
        const float* __restrict__ hard,
        const float* __restrict__ w1, const float* __restrict__ b1,
        const float* __restrict__ w2, const float* __restrict__ b2,
        const float* __restrict__ W0, const float* __restrict__ asrc,
        const float* __restrict__ adst,
        unsigned* __restrict__ bmT,
        float* __restrict__ x, float* __restrict__ hwA,
        float* __restrict__ ssA, float* __restrict__ sdA,
        float* __restrict__ accum, int* __restrict__ done) {
    int wave = threadIdx.x >> 6;
    int lane = threadIdx.x & 63;
    if (blockIdx.x < 512) {
        int t    = blockIdx.x * 256 + threadIdx.x;   // 0..131071
        int cg   = t & 1023;                          // col group (4 cols)
        int band = t >> 10;                           // 0..127
        int i0   = cg * 4;
        int jbase = band * BANDSZ;
        unsigned m0 = 0u, m1 = 0u, m2 = 0u, m3 = 0u;
        #pragma unroll
        for (int batch = 0; batch < 4; ++batch) {
            float4 a[8];
            #pragma unroll
            for (int u = 0; u < 8; ++u)
                a[u] = adj4[(size_t)(jbase + batch * 8 + u) * 1024 + cg];
            #pragma unroll
            for (int u = 0; u < 8; ++u) {
                unsigned bit = batch * 8 + u;
                m0 |= (unsigned)(a[u].x != 0.f) << bit;
                m1 |= (unsigned)(a[u].y != 0.f) << bit;
                m2 |= (unsigned)(a[u].z != 0.f) << bit;
                m3 |= (unsigned)(a[u].w != 0.f) << bit;
            }
        }
        bmT[(i0 + 0) * NB + band] = m0;
        bmT[(i0 + 1) * NB + band] = m1;
        bmT[(i0 + 2) * NB + band] = m2;
        bmT[(i0 + 3) * NB + band] = m3;
        if (blockIdx.x == 0 && threadIdx.x == 0) { *accum = 0.f; *done = 0; }
    } else {
        int row = (blockIdx.x - 512) * 4 + wave;      // one row per wave
        float ts = (float)(*timestep);
        float pr = (ts - arr[row]) / (dep[row] - arr[row]);
        float hd = hard[row];
        float t  = pr * w1[lane] + hd * w1[64 + lane] + b1[lane];
        float xv = b2[lane];
        #pragma unroll
        for (int k = 0; k < 64; ++k)
            xv += __shfl(t, k, 64) * w2[k * 64 + lane];
        x[row * 64 + lane] = xv;
        float tr = transform_row(xv, W0, lane);
        hwA[row * 64 + lane] = tr;
        float s1 = wave_reduce_sum(tr * asrc[lane]);
        float s2 = wave_reduce_sum(tr * adst[lane]);
        if (lane == 0) { ssA[row] = s1; sdA[row] = s2; }
    }
}

// ---- dispatch 2: mask->index compaction + layer-0 aggregate + relu +
// layer-1 transform + scores. 4-WAVE-PER-ROW (1024 thr): all 4 waves of a
// row redundantly extract the identical index list (benign same-value LDS
// writes), gather split into quarters, partials combined via LDS;
// quarter-0 wave does epilogue + stores.
__global__ void __launch_bounds__(1024, 8) compact_agg_tr(
        const unsigned* __restrict__ bmT,
        const float* __restrict__ hwin, const float* __restrict__ ssin,
        const float* __restrict__ sdin, const float* __restrict__ b,
        const float* __restrict__ W, const float* __restrict__ asrc,
        const float* __restrict__ adst,
        int* __restrict__ nbr_c, int* __restrict__ deg_arr,
        float* __restrict__ hwout, float* __restrict__ ssout,
        float* __restrict__ sdout) {
    __shared__ int lds[4][MAXDEG];
    __shared__ float accb[4][3][64];
    int w    = threadIdx.x >> 6;      // 0..15
    int lane = threadIdx.x & 63;
    int r    = w >> 2;                // row slot 0..3
    int q    = w & 3;                 // quarter 0..3
    int i = blockIdx.x * 4 + r;
    uint2 mv = *(const uint2*)(bmT + i * NB + 2 * lane);   // bands 2l, 2l+1
    unsigned m0 = mv.x, m1 = mv.y;
    int selfband = i >> 5;                    // self-loop: bit i&31 of band i>>5
    if (2 * lane     == selfband) m0 |= 1u << (i & 31);
    if (2 * lane + 1 == selfband) m1 |= 1u << (i & 31);
    int c0 = __popc(m0);
    int c1 = __popc(m1);
    int c  = c0 + c1;
    int inc = c;
    #pragma unroll
    for (int s = 1; s < 64; s <<= 1) {
        int t = __shfl_up(inc, s, 64);
        if (lane >= s) inc += t;
    }
    int off = inc - c;
    int deg = min(__shfl(inc, 63, 64), MAXDEG);
    {   // all 4 waves write identical values — benign duplicate stores
        int o = off;
        unsigned mm = m0; int base = (2 * lane) * 32;
        while (mm) { int bit = __ffs(mm) - 1; mm &= mm - 1;
                     if (o < MAXDEG) lds[r][o] = base + bit; ++o; }
        mm = m1; base = (2 * lane + 1) * 32;
        while (mm) { int bit = __ffs(mm) - 1; mm &= mm - 1;
                     if (o < MAXDEG) lds[r][o] = base + bit; ++o; }
    }
    __syncthreads();
    int j0 = (lane < deg)      ? lds[r][lane]      : 0;
    int j1 = (lane + 64 < deg) ? lds[r][lane + 64] : 0;
    if (q == 0) {
        if (lane < deg)      nbr_c[i * MAXDEG + lane]      = j0;
        if (lane + 64 < deg) nbr_c[i * MAXDEG + lane + 64] = j1;
        if (lane == 0) deg_arr[i] = deg;
    }
    int qsz = (deg + 3) >> 2;
    int lo  = q * qsz;
    int hi  = min(lo + qsz, deg);
    float Z;
    float acc = agg_part(j0, j1, deg, sdin[i], ssin, hwin, lane, lo, hi, &Z);
    if (q) accb[r][q - 1][lane] = acc;
    __syncthreads();
    if (q == 0) {
        acc = ((acc + accb[r][0][lane]) + accb[r][1][lane]) + accb[r][2][lane];
        float hv = fmaxf(acc / Z + b[lane], 0.f);
        float tr = transform_row(hv, W, lane);
        hwout[i * 64 + lane] = tr;
        float s1 = wave_reduce_sum(tr * asrc[lane]);
        float s2 = wave_reduce_sum(tr * adst[lane]);
        if (lane == 0) { ssout[i] = s1; sdout[i] = s2; }
    }
}

// ---- dispatch 3: layer-1 aggregate + relu + layer-2 transform + scores.
// 4-wave-per-row split (1024 thr).
__global__ void __launch_bounds__(1024, 8) agg_tr(
        const float* __restrict__ hwin, const float* __restrict__ ssin,
        const float* __restrict__ sdin, const int* __restrict__ nbr_c,
        const int* __restrict__ deg_arr, const float* __restrict__ b,
        const float* __restrict__ W, const float* __restrict__ asrc,
        const float* __restrict__ adst,
        float* __restrict__ hwout, float* __restrict__ ssout,
        float* __restrict__ sdout) {
    __shared__ float accb[4][3][64];
    int w    = threadIdx.x >> 6;      // 0..15
    int lane = threadIdx.x & 63;
    int r    = w >> 2;                // row slot 0..3
    int q    = w & 3;                 // quarter 0..3
    int i = blockIdx.x * 4 + r;
    int deg = deg_arr[i];
    int j0 = (lane < deg)      ? nbr_c[i * MAXDEG + lane]      : 0;
    int j1 = (lane + 64 < deg) ? nbr_c[i * MAXDEG + lane + 64] : 0;
    int qsz = (deg + 3) >> 2;
    int lo  = q * qsz;
    int hi  = min(lo + qsz, deg);
    float Z;
    float acc = agg_part(j0, j1, deg, sdin[i], ssin, hwin, lane, lo, hi, &Z);
    if (q) accb[r][q - 1][lane] = acc;
    __syncthreads();
    if (q == 0) {
        acc = ((acc + accb[r][0][lane]) + accb[r][1][lane]) + accb[r][2][lane];
        float hv = fmaxf(acc / Z + b[lane], 0.f);
        float tr = transform_row(hv, W, lane);
        hwout[i * 64 + lane] = tr;
        float s1 = wave_reduce_sum(tr * asrc[lane]);
        float s2 = wave_reduce_sum(tr * adst[lane]);
        if (lane == 0) { ssout[i] = s1; sdout[i] = s2; }
    }
}

// ---- dispatch 4: layer-2 aggregate + residual + layernorm + val_w dot +
// block atomicAdd + last-block finish. 4-wave-per-row split (1024 thr).
__global__ void __launch_bounds__(1024, 8) agg_final_finish(
        const float* __restrict__ hwin, const float* __restrict__ ssin,
        const float* __restrict__ sdin, const int* __restrict__ nbr_c,
        const int* __restrict__ deg_arr, const float* __restrict__ b,
        const float* __restrict__ x, const float* __restrict__ vw,
        const float* __restrict__ vb,
        float* __restrict__ accum, int* __restrict__ done,
        float* __restrict__ out) {
    __shared__ float accb[4][3][64];
    __shared__ float sp[4];
    int w    = threadIdx.x >> 6;
    int lane = threadIdx.x & 63;
    int r    = w >> 2;
    int q    = w & 3;
    int i = blockIdx.x * 4 + r;
    int deg = deg_arr[i];
    int j0 = (lane < deg)      ? nbr_c[i * MAXDEG + lane]      : 0;
    int j1 = (lane + 64 < deg) ? nbr_c[i * MAXDEG + lane + 64] : 0;
    int qsz = (deg + 3) >> 2;
    int lo  = q * qsz;
    int hi  = min(lo + qsz, deg);
    float Z;
    float acc = agg_part(j0, j1, deg, sdin[i], ssin, hwin, lane, lo, hi, &Z);
    if (q) accb[r][q - 1][lane] = acc;
    __syncthreads();
    if (q == 0) {
        acc = ((acc + accb[r][0][lane]) + accb[r][1][lane]) + accb[r][2][lane];
        float hv = acc / Z + b[lane];
        float v  = x[i * 64 + lane] + hv;
        float mu = wave_reduce_sum(v) * (1.f / 64.f);
        float d  = v - mu;
        float var = wave_reduce_sum(d * d) * (1.f / 64.f);
        float ln  = d * rsqrtf(var + LN_EPS);
        float part = wave_reduce_sum(ln * vw[lane]);
        if (lane == 0) sp[r] = part;
    }
    __syncthreads();
    if (threadIdx.x == 0) {
        float bp = sp[0] + sp[1] + sp[2] + sp[3];
        atomicAdd(accum, bp);
        __threadfence();
        int old = atomicAdd(done, 1);
        if (old == (N / 4) - 1) {
            float t = __hip_atomic_load(accum, __ATOMIC_RELAXED,
                                        __HIP_MEMORY_SCOPE_AGENT);
            out[0] = fmaxf(t * (1.f / (float)N) + vb[0], 0.f);
        }
    }
}

extern "C" void kernel_launch(void* const* d_in, const int* in_sizes, int n_in,
                              void* d_out, int out_size, void* d_ws, size_t ws_size,
                              hipStream_t stream) {
    const float4* adj4      = (const float4*)d_in[0];
    const int*   timestep   = (const int*)  d_in[1];
    const float* arrivals   = (const float*)d_in[2];
    const float* departures = (const float*)d_in[3];
    const float* hard       = (const float*)d_in[4];
    // d_in[5] active_agents: unused by reference
    const float* emb_w1     = (const float*)d_in[6];
    const float* emb_b1     = (const float*)d_in[7];
    const float* emb_w2     = (const float*)d_in[8];
    const float* emb_b2     = (const float*)d_in[9];
    const float* gat_w      = (const float*)d_in[10];
    const float* gat_asrc   = (const float*)d_in[11];
    const float* gat_adst   = (const float*)d_in[12];
    const float* gat_b      = (const float*)d_in[13];
    const float* val_w      = (const float*)d_in[14];
    const float* val_b      = (const float*)d_in[15];

    const size_t MB = 1u << 20;
    char* ws = (char*)d_ws;
    unsigned* bmT  = (unsigned*)(ws);              // 2 MB (4096 cols x 128 bands)
    int*   nbr_c   = (int*)  (ws + 4 * MB);        // 2 MB
    int*   deg_arr = (int*)  (ws + 6 * MB);        // 16 KB
    float* x       = (float*)(ws + 7 * MB);        // 1 MB
    float* hwA     = (float*)(ws + 8 * MB);        // 1 MB
    float* hwB     = (float*)(ws + 9 * MB);        // 1 MB
    float* ssA     = (float*)(ws + 10 * MB);
    float* sdA     = (float*)(ws + 10 * MB + 65536);
    float* ssB     = (float*)(ws + 10 * MB + 131072);
    float* sdB     = (float*)(ws + 10 * MB + 196608);
    float* accum   = (float*)(ws + 11 * MB);
    int*   done    = (int*)  (ws + 11 * MB + 64);

    prep_kernel<<<1536, 256, 0, stream>>>(adj4, timestep, arrivals, departures, hard,
                                          emb_w1, emb_b1, emb_w2, emb_b2,
                                          gat_w, gat_asrc, gat_adst,
                                          bmT, x, hwA, ssA, sdA, accum, done);
    compact_agg_tr<<<N / 4, 1024, 0, stream>>>(bmT, hwA, ssA, sdA, gat_b,
                                               gat_w + 64 * 64, gat_asrc + 64,
                                               gat_adst + 64,
                                               nbr_c, deg_arr, hwB, ssB, sdB);
    agg_tr<<<N / 4, 1024, 0, stream>>>(hwB, ssB, sdB, nbr_c, deg_arr, gat_b + 64,
                                       gat_w + 2 * 64 * 64, gat_asrc + 128,
                                       gat_adst + 128, hwA, ssA, sdA);
    agg_final_finish<<<N / 4, 1024, 0, stream>>>(hwA, ssA, sdA, nbr_c, deg_arr,
                                                 gat_b + 128, x, val_w, val_b,
                                                 accum, done, (float*)d_out);
    (void)in_sizes; (void)n_in; (void)out_size; (void)ws_size;
}

// Round 8
// 171.510 us; speedup vs baseline: 1.1591x; 1.1591x over previous
//
#include <hip/hip_runtime.h>
#include <math.h>

#define N 4096
#define NB 128         // bands per column
#define BANDSZ 32      // rows per band
#define MAXDEG 128
#define NEG_SLOPE 0.2f
#define LN_EPS 1e-5f

__device__ __forceinline__ float wave_reduce_sum(float v) {
    #pragma unroll
    for (int m = 32; m >= 1; m >>= 1) v += __shfl_xor(v, m, 64);
    return v;
}
__device__ __forceinline__ float wave_reduce_max(float v) {
    #pragma unroll
    for (int m = 32; m >= 1; m >>= 1) v = fmaxf(v, __shfl_xor(v, m, 64));
    return v;
}

// row-vector (lane=col) times 64x64 row-major W via shfl broadcast.
__device__ __forceinline__ float transform_row(float hv, const float* __restrict__ W,
                                               int lane) {
    float tr = 0.f;
    #pragma unroll
    for (int k = 0; k < 64; ++k)
        tr += __shfl(hv, k, 64) * W[k * 64 + lane];
    return tr;
}

// softmax over neighbors (j0: first 64, j1: next 64, deg total) + weighted
// aggregation of hwin rows + bias. Used by dispatch 2 (verified, R5).
__device__ __forceinline__ float agg_core(int j0, int j1, int deg, float sd,
        const float* __restrict__ ssin, const float* __restrict__ hwin,
        const float* __restrict__ b, int lane) {
    float e0 = -1e30f, e1 = -1e30f;
    if (lane < deg)      { float v = ssin[j0] + sd; e0 = v > 0.f ? v : NEG_SLOPE * v; }
    if (lane + 64 < deg) { float v = ssin[j1] + sd; e1 = v > 0.f ? v : NEG_SLOPE * v; }
    float m = wave_reduce_max(fmaxf(e0, e1));
    float p0 = (lane < deg)      ? expf(e0 - m) : 0.f;
    float p1 = (lane + 64 < deg) ? expf(e1 - m) : 0.f;
    float Z = wave_reduce_sum(p0 + p1);
    float acc = 0.f;
    int d0 = min(deg, 64);
    #pragma unroll 4
    for (int n = 0; n < d0; ++n) {
        int   jj = __shfl(j0, n, 64);
        float p  = __shfl(p0, n, 64);
        acc += p * hwin[jj * 64 + lane];
    }
    for (int n = 64; n < deg; ++n) {
        int   jj = __shfl(j1, n - 64, 64);
        float p  = __shfl(p1, n - 64, 64);
        acc += p * hwin[jj * 64 + lane];
    }
    return acc / Z + b[lane];
}

// Half-gather for the 2-wave-per-row split (dispatches 3/4). Softmax probs
// computed redundantly+identically in both waves; partial acc via LDS.
// Association order matches the verified R4/R5 split (absmax 0.0).
__device__ __forceinline__ float agg_half(int j0, int j1, int deg, float sd,
        const float* __restrict__ ssin, const float* __restrict__ hwin,
        int lane, int lo, int hi, float* Zout) {
    float e0 = -1e30f, e1 = -1e30f;
    if (lane < deg)      { float v = ssin[j0] + sd; e0 = v > 0.f ? v : NEG_SLOPE * v; }
    if (lane + 64 < deg) { float v = ssin[j1] + sd; e1 = v > 0.f ? v : NEG_SLOPE * v; }
    float m = wave_reduce_max(fmaxf(e0, e1));
    float p0 = (lane < deg)      ? expf(e0 - m) : 0.f;
    float p1 = (lane + 64 < deg) ? expf(e1 - m) : 0.f;
    *Zout = wave_reduce_sum(p0 + p1);
    float acc = 0.f;
    int hi0 = min(hi, 64);
    #pragma unroll 8
    for (int n = lo; n < hi0; ++n) {          // slots below 64
        int   jj = __shfl(j0, n, 64);
        float p  = __shfl(p0, n, 64);
        acc += p * hwin[jj * 64 + lane];
    }
    #pragma unroll 2
    for (int n = (lo > 64 ? lo : 64); n < hi; ++n) {   // slots >= 64
        int   jj = __shfl(j1, n - 64, 64);
        float p  = __shfl(p1, n - 64, 64);
        acc += p * hwin[jj * 64 + lane];
    }
    return acc;
}

// ---- dispatch 1: BITMASK neighbor build (bm[band][col], uint4 coalesced
// store) + emb MLP + layer-0 transform. Verified R5 structure (186.1 µs).
__global__ void __launch_bounds__(256) prep_kernel(
        const float4* __restrict__ adj4, const int* __restrict__ timestep,
        const float* __restrict__ arr, const float* __restrict__ dep,
        const float* __restrict__ hard,
        const float* __restrict__ w1, const float* __restrict__ b1,
        const float* __restrict__ w2, const float* __restrict__ b2,
        const float* __restrict__ W0, const float* __restrict__ asrc,
        const float* __restrict__ adst,
        uint4* __restrict__ bm4,
        float* __restrict__ x, float* __restrict__ hwA,
        float* __restrict__ ssA, float* __restrict__ sdA) {
    int wave = threadIdx.x >> 6;
    int lane = threadIdx.x & 63;
    if (blockIdx.x < 512) {
        int t    = blockIdx.x * 256 + threadIdx.x;   // 0..131071
        int cg   = t & 1023;                          // col group (4 cols)
        int band = t >> 10;                           // 0..127
        int jbase = band * BANDSZ;
        unsigned m0 = 0u, m1 = 0u, m2 = 0u, m3 = 0u;
        #pragma unroll
        for (int batch = 0; batch < 4; ++batch) {
            float4 a[8];
            #pragma unroll
            for (int u = 0; u < 8; ++u)
                a[u] = adj4[(size_t)(jbase + batch * 8 + u) * 1024 + cg];
            #pragma unroll
            for (int u = 0; u < 8; ++u) {
                unsigned bit = batch * 8 + u;
                m0 |= (unsigned)(a[u].x != 0.f) << bit;
                m1 |= (unsigned)(a[u].y != 0.f) << bit;
                m2 |= (unsigned)(a[u].z != 0.f) << bit;
                m3 |= (unsigned)(a[u].w != 0.f) << bit;
            }
        }
        uint4 m; m.x = m0; m.y = m1; m.z = m2; m.w = m3;
        bm4[band * 1024 + cg] = m;                    // bm[band][i0..i0+3]
    } else {
        int row = (blockIdx.x - 512) * 4 + wave;      // one row per wave
        float ts = (float)(*timestep);
        float pr = (ts - arr[row]) / (dep[row] - arr[row]);
        float hd = hard[row];
        float t  = pr * w1[lane] + hd * w1[64 + lane] + b1[lane];
        float xv = b2[lane];
        #pragma unroll
        for (int k = 0; k < 64; ++k)
            xv += __shfl(t, k, 64) * w2[k * 64 + lane];
        x[row * 64 + lane] = xv;
        float tr = transform_row(xv, W0, lane);
        hwA[row * 64 + lane] = tr;
        float s1 = wave_reduce_sum(tr * asrc[lane]);
        float s2 = wave_reduce_sum(tr * adst[lane]);
        if (lane == 0) { ssA[row] = s1; sdA[row] = s2; }
    }
}

// ---- dispatch 2: mask->index compaction (popc + wave prefix scan +
// LSB-first extract) + layer-0 aggregate + relu + layer-1 transform +
// scores. Verified R5 structure.
__global__ void __launch_bounds__(256) compact_agg_tr(
        const unsigned* __restrict__ bm,
        const float* __restrict__ hwin, const float* __restrict__ ssin,
        const float* __restrict__ sdin, const float* __restrict__ b,
        const float* __restrict__ W, const float* __restrict__ asrc,
        const float* __restrict__ adst,
        int* __restrict__ nbr_c, int* __restrict__ deg_arr,
        float* __restrict__ hwout, float* __restrict__ ssout,
        float* __restrict__ sdout) {
    __shared__ int lds[4][MAXDEG];
    int wave = threadIdx.x >> 6;
    int lane = threadIdx.x & 63;
    int i = blockIdx.x * 4 + wave;
    unsigned m0 = bm[(2 * lane)     * N + i];
    unsigned m1 = bm[(2 * lane + 1) * N + i];
    int selfband = i >> 5;                    // self-loop: bit i&31 of band i>>5
    if (2 * lane     == selfband) m0 |= 1u << (i & 31);
    if (2 * lane + 1 == selfband) m1 |= 1u << (i & 31);
    int c0 = __popc(m0);
    int c1 = __popc(m1);
    int c  = c0 + c1;
    int inc = c;
    #pragma unroll
    for (int s = 1; s < 64; s <<= 1) {
        int t = __shfl_up(inc, s, 64);
        if (lane >= s) inc += t;
    }
    int off = inc - c;
    int deg = min(__shfl(inc, 63, 64), MAXDEG);
    {
        int o = off;
        unsigned mm = m0; int base = (2 * lane) * 32;
        while (mm) { int bit = __ffs(mm) - 1; mm &= mm - 1;
                     if (o < MAXDEG) lds[wave][o] = base + bit; ++o; }
        mm = m1; base = (2 * lane + 1) * 32;
        while (mm) { int bit = __ffs(mm) - 1; mm &= mm - 1;
                     if (o < MAXDEG) lds[wave][o] = base + bit; ++o; }
    }
    __syncthreads();
    int j0 = (lane < deg)      ? lds[wave][lane]      : 0;
    int j1 = (lane + 64 < deg) ? lds[wave][lane + 64] : 0;
    if (lane < deg)      nbr_c[i * MAXDEG + lane]      = j0;
    if (lane + 64 < deg) nbr_c[i * MAXDEG + lane + 64] = j1;
    if (lane == 0) deg_arr[i] = deg;
    float hv = fmaxf(agg_core(j0, j1, deg, sdin[i], ssin, hwin, b, lane), 0.f);
    float tr = transform_row(hv, W, lane);
    hwout[i * 64 + lane] = tr;
    float s1 = wave_reduce_sum(tr * asrc[lane]);
    float s2 = wave_reduce_sum(tr * adst[lane]);
    if (lane == 0) { ssout[i] = s1; sdout[i] = s2; }
}

// ---- dispatch 3: layer-1 aggregate + relu + layer-2 transform + scores.
// 512-thr blocks, wave-pair per row (verified R4/R5: absmax 0.0).
__global__ void __launch_bounds__(512, 8) agg_tr(
        const float* __restrict__ hwin, const float* __restrict__ ssin,
        const float* __restrict__ sdin, const int* __restrict__ nbr_c,
        const int* __restrict__ deg_arr, const float* __restrict__ b,
        const float* __restrict__ W, const float* __restrict__ asrc,
        const float* __restrict__ adst,
        float* __restrict__ hwout, float* __restrict__ ssout,
        float* __restrict__ sdout) {
    __shared__ float accb[4][64];
    int w    = threadIdx.x >> 6;      // 0..7
    int lane = threadIdx.x & 63;
    int r    = w >> 1;                // row slot 0..3
    int half = w & 1;
    int i = blockIdx.x * 4 + r;
    int deg = deg_arr[i];
    int j0 = (lane < deg)      ? nbr_c[i * MAXDEG + lane]      : 0;
    int j1 = (lane + 64 < deg) ? nbr_c[i * MAXDEG + lane + 64] : 0;
    int h  = (deg + 1) >> 1;
    float Z;
    float acc = agg_half(j0, j1, deg, sdin[i], ssin, hwin, lane,
                         half ? h : 0, half ? deg : h, &Z);
    if (half) accb[r][lane] = acc;
    __syncthreads();
    if (!half) {
        acc += accb[r][lane];
        float hv = fmaxf(acc / Z + b[lane], 0.f);
        float tr = transform_row(hv, W, lane);
        hwout[i * 64 + lane] = tr;
        float s1 = wave_reduce_sum(tr * asrc[lane]);
        float s2 = wave_reduce_sum(tr * adst[lane]);
        if (lane == 0) { ssout[i] = s1; sdout[i] = s2; }
    }
}

// ---- dispatch 4: layer-2 aggregate + residual + layernorm + val_w dot.
// ATOMIC-FREE finish: each block plain-stores its partial; a tiny 5th
// kernel reduces. (Replaces 2048 serialized single-line agent atomics +
// 1024 threadfences — suspected 15-25 µs hidden cost.)
__global__ void __launch_bounds__(512, 8) agg_final(
        const float* __restrict__ hwin, const float* __restrict__ ssin,
        const float* __restrict__ sdin, const int* __restrict__ nbr_c,
        const int* __restrict__ deg_arr, const float* __restrict__ b,
        const float* __restrict__ x, const float* __restrict__ vw,
        float* __restrict__ partials) {
    __shared__ float accb[4][64];
    __shared__ float sp[4];
    int w    = threadIdx.x >> 6;
    int lane = threadIdx.x & 63;
    int r    = w >> 1;
    int half = w & 1;
    int i = blockIdx.x * 4 + r;
    int deg = deg_arr[i];
    int j0 = (lane < deg)      ? nbr_c[i * MAXDEG + lane]      : 0;
    int j1 = (lane + 64 < deg) ? nbr_c[i * MAXDEG + lane + 64] : 0;
    int h  = (deg + 1) >> 1;
    float Z;
    float acc = agg_half(j0, j1, deg, sdin[i], ssin, hwin, lane,
                         half ? h : 0, half ? deg : h, &Z);
    if (half) accb[r][lane] = acc;
    __syncthreads();
    if (!half) {
        acc += accb[r][lane];
        float hv = acc / Z + b[lane];
        float v  = x[i * 64 + lane] + hv;
        float mu = wave_reduce_sum(v) * (1.f / 64.f);
        float d  = v - mu;
        float var = wave_reduce_sum(d * d) * (1.f / 64.f);
        float ln  = d * rsqrtf(var + LN_EPS);
        float part = wave_reduce_sum(ln * vw[lane]);
        if (lane == 0) sp[r] = part;
    }
    __syncthreads();
    if (threadIdx.x == 0)
        partials[blockIdx.x] = sp[0] + sp[1] + sp[2] + sp[3];
}

// ---- dispatch 5: reduce 1024 block partials (fixed order) + relu.
__global__ void __launch_bounds__(256) finish_kernel(
        const float* __restrict__ partials, const float* __restrict__ vb,
        float* __restrict__ out) {
    __shared__ float sw[4];
    int lane = threadIdx.x & 63;
    int wave = threadIdx.x >> 6;
    float s = partials[threadIdx.x] + partials[threadIdx.x + 256]
            + partials[threadIdx.x + 512] + partials[threadIdx.x + 768];
    s = wave_reduce_sum(s);
    if (lane == 0) sw[wave] = s;
    __syncthreads();
    if (threadIdx.x == 0) {
        float t = sw[0] + sw[1] + sw[2] + sw[3];
        out[0] = fmaxf(t * (1.f / (float)N) + vb[0], 0.f);
    }
}

extern "C" void kernel_launch(void* const* d_in, const int* in_sizes, int n_in,
                              void* d_out, int out_size, void* d_ws, size_t ws_size,
                              hipStream_t stream) {
    const float4* adj4      = (const float4*)d_in[0];
    const int*   timestep   = (const int*)  d_in[1];
    const float* arrivals   = (const float*)d_in[2];
    const float* departures = (const float*)d_in[3];
    const float* hard       = (const float*)d_in[4];
    // d_in[5] active_agents: unused by reference
    const float* emb_w1     = (const float*)d_in[6];
    const float* emb_b1     = (const float*)d_in[7];
    const float* emb_w2     = (const float*)d_in[8];
    const float* emb_b2     = (const float*)d_in[9];
    const float* gat_w      = (const float*)d_in[10];
    const float* gat_asrc   = (const float*)d_in[11];
    const float* gat_adst   = (const float*)d_in[12];
    const float* gat_b      = (const float*)d_in[13];
    const float* val_w      = (const float*)d_in[14];
    const float* val_b      = (const float*)d_in[15];

    const size_t MB = 1u << 20;
    char* ws = (char*)d_ws;
    unsigned* bm   = (unsigned*)(ws);              // 2 MB (128 bands x 4096 cols)
    int*   nbr_c   = (int*)  (ws + 4 * MB);        // 2 MB
    int*   deg_arr = (int*)  (ws + 6 * MB);        // 16 KB
    float* x       = (float*)(ws + 7 * MB);        // 1 MB
    float* hwA     = (float*)(ws + 8 * MB);        // 1 MB
    float* hwB     = (float*)(ws + 9 * MB);        // 1 MB
    float* ssA     = (float*)(ws + 10 * MB);
    float* sdA     = (float*)(ws + 10 * MB + 65536);
    float* ssB     = (float*)(ws + 10 * MB + 131072);
    float* sdB     = (float*)(ws + 10 * MB + 196608);
    float* partials= (float*)(ws + 11 * MB);       // 4 KB (1024 floats)

    prep_kernel<<<1536, 256, 0, stream>>>(adj4, timestep, arrivals, departures, hard,
                                          emb_w1, emb_b1, emb_w2, emb_b2,
                                          gat_w, gat_asrc, gat_adst,
                                          (uint4*)bm, x, hwA, ssA, sdA);
    compact_agg_tr<<<N / 4, 256, 0, stream>>>(bm, hwA, ssA, sdA, gat_b,
                                              gat_w + 64 * 64, gat_asrc + 64,
                                              gat_adst + 64,
                                              nbr_c, deg_arr, hwB, ssB, sdB);
    agg_tr<<<N / 4, 512, 0, stream>>>(hwB, ssB, sdB, nbr_c, deg_arr, gat_b + 64,
                                      gat_w + 2 * 64 * 64, gat_asrc + 128,
                                      gat_adst + 128, hwA, ssA, sdA);
    agg_final<<<N / 4, 512, 0, stream>>>(hwA, ssA, sdA, nbr_c, deg_arr,
                                         gat_b + 128, x, val_w, partials);
    finish_kernel<<<1, 256, 0, stream>>>(partials, val_b, (float*)d_out);
    (void)in_sizes; (void)n_in; (void)out_size; (void)ws_size;
}

// Round 9
// 167.209 us; speedup vs baseline: 1.1890x; 1.0257x over previous
//
#include <hip/hip_runtime.h>
#include <math.h>

#define N 4096
#define NB 128         // bands per column
#define BANDSZ 32      // rows per band
#define MAXDEG 128
#define NEG_SLOPE 0.2f
#define LN_EPS 1e-5f

__device__ __forceinline__ float wave_reduce_sum(float v) {
    #pragma unroll
    for (int m = 32; m >= 1; m >>= 1) v += __shfl_xor(v, m, 64);
    return v;
}
__device__ __forceinline__ float wave_reduce_max(float v) {
    #pragma unroll
    for (int m = 32; m >= 1; m >>= 1) v = fmaxf(v, __shfl_xor(v, m, 64));
    return v;
}

// row-vector (lane=col) times 64x64 row-major W via shfl broadcast.
__device__ __forceinline__ float transform_row(float hv, const float* __restrict__ W,
                                               int lane) {
    float tr = 0.f;
    #pragma unroll
    for (int k = 0; k < 64; ++k)
        tr += __shfl(hv, k, 64) * W[k * 64 + lane];
    return tr;
}

// Half-gather for the 2-wave-per-row split (dispatches 2/3/4). Softmax probs
// computed redundantly+identically in both waves; partial acc via LDS.
// Association order matches the verified R4/R5 split (absmax 0.0).
__device__ __forceinline__ float agg_half(int j0, int j1, int deg, float sd,
        const float* __restrict__ ssin, const float* __restrict__ hwin,
        int lane, int lo, int hi, float* Zout) {
    float e0 = -1e30f, e1 = -1e30f;
    if (lane < deg)      { float v = ssin[j0] + sd; e0 = v > 0.f ? v : NEG_SLOPE * v; }
    if (lane + 64 < deg) { float v = ssin[j1] + sd; e1 = v > 0.f ? v : NEG_SLOPE * v; }
    float m = wave_reduce_max(fmaxf(e0, e1));
    float p0 = (lane < deg)      ? expf(e0 - m) : 0.f;
    float p1 = (lane + 64 < deg) ? expf(e1 - m) : 0.f;
    *Zout = wave_reduce_sum(p0 + p1);
    float acc = 0.f;
    int hi0 = min(hi, 64);
    #pragma unroll 8
    for (int n = lo; n < hi0; ++n) {          // slots below 64
        int   jj = __shfl(j0, n, 64);
        float p  = __shfl(p0, n, 64);
        acc += p * hwin[jj * 64 + lane];
    }
    #pragma unroll 2
    for (int n = (lo > 64 ? lo : 64); n < hi; ++n) {   // slots >= 64
        int   jj = __shfl(j1, n - 64, 64);
        float p  = __shfl(p1, n - 64, 64);
        acc += p * hwin[jj * 64 + lane];
    }
    return acc;
}

// ---- dispatch 1: BITMASK neighbor build (bm[band][col], uint4 coalesced
// store) + emb MLP + layer-0 transform. Verified R5/R8 structure.
__global__ void __launch_bounds__(256) prep_kernel(
        const float4* __restrict__ adj4, const int* __restrict__ timestep,
        const float* __restrict__ arr, const float* __restrict__ dep,
        const float* __restrict__ hard,
        const float* __restrict__ w1, const float* __restrict__ b1,
        const float* __restrict__ w2, const float* __restrict__ b2,
        const float* __restrict__ W0, const float* __restrict__ asrc,
        const float* __restrict__ adst,
        uint4* __restrict__ bm4,
        float* __restrict__ x, float* __restrict__ hwA,
        float* __restrict__ ssA, float* __restrict__ sdA) {
    int wave = threadIdx.x >> 6;
    int lane = threadIdx.x & 63;
    if (blockIdx.x < 512) {
        int t    = blockIdx.x * 256 + threadIdx.x;   // 0..131071
        int cg   = t & 1023;                          // col group (4 cols)
        int band = t >> 10;                           // 0..127
        int jbase = band * BANDSZ;
        unsigned m0 = 0u, m1 = 0u, m2 = 0u, m3 = 0u;
        #pragma unroll
        for (int batch = 0; batch < 4; ++batch) {
            float4 a[8];
            #pragma unroll
            for (int u = 0; u < 8; ++u)
                a[u] = adj4[(size_t)(jbase + batch * 8 + u) * 1024 + cg];
            #pragma unroll
            for (int u = 0; u < 8; ++u) {
                unsigned bit = batch * 8 + u;
                m0 |= (unsigned)(a[u].x != 0.f) << bit;
                m1 |= (unsigned)(a[u].y != 0.f) << bit;
                m2 |= (unsigned)(a[u].z != 0.f) << bit;
                m3 |= (unsigned)(a[u].w != 0.f) << bit;
            }
        }
        uint4 m; m.x = m0; m.y = m1; m.z = m2; m.w = m3;
        bm4[band * 1024 + cg] = m;                    // bm[band][i0..i0+3]
    } else {
        int row = (blockIdx.x - 512) * 4 + wave;      // one row per wave
        float ts = (float)(*timestep);
        float pr = (ts - arr[row]) / (dep[row] - arr[row]);
        float hd = hard[row];
        float t  = pr * w1[lane] + hd * w1[64 + lane] + b1[lane];
        float xv = b2[lane];
        #pragma unroll
        for (int k = 0; k < 64; ++k)
            xv += __shfl(t, k, 64) * w2[k * 64 + lane];
        x[row * 64 + lane] = xv;
        float tr = transform_row(xv, W0, lane);
        hwA[row * 64 + lane] = tr;
        float s1 = wave_reduce_sum(tr * asrc[lane]);
        float s2 = wave_reduce_sum(tr * adst[lane]);
        if (lane == 0) { ssA[row] = s1; sdA[row] = s2; }
    }
}

// ---- dispatch 2: mask->index compaction + layer-0 aggregate + relu +
// layer-1 transform + scores. WAVE-PAIR split (512 thr), keeping the R5
// bm[band][col] layout (isolates the split from R6's transpose): both
// waves of a pair redundantly extract the identical index list (benign
// same-value LDS writes), gather split [0,h)/[h,deg); half-0 epilogue.
__global__ void __launch_bounds__(512, 8) compact_agg_tr(
        const unsigned* __restrict__ bm,
        const float* __restrict__ hwin, const float* __restrict__ ssin,
        const float* __restrict__ sdin, const float* __restrict__ b,
        const float* __restrict__ W, const float* __restrict__ asrc,
        const float* __restrict__ adst,
        int* __restrict__ nbr_c, int* __restrict__ deg_arr,
        float* __restrict__ hwout, float* __restrict__ ssout,
        float* __restrict__ sdout) {
    __shared__ int lds[4][MAXDEG];
    __shared__ float accb[4][64];
    int w    = threadIdx.x >> 6;      // 0..7
    int lane = threadIdx.x & 63;
    int r    = w >> 1;                // row slot 0..3
    int half = w & 1;
    int i = blockIdx.x * 4 + r;
    unsigned m0 = bm[(2 * lane)     * N + i];
    unsigned m1 = bm[(2 * lane + 1) * N + i];
    int selfband = i >> 5;                    // self-loop: bit i&31 of band i>>5
    if (2 * lane     == selfband) m0 |= 1u << (i & 31);
    if (2 * lane + 1 == selfband) m1 |= 1u << (i & 31);
    int c0 = __popc(m0);
    int c1 = __popc(m1);
    int c  = c0 + c1;
    int inc = c;
    #pragma unroll
    for (int s = 1; s < 64; s <<= 1) {
        int t = __shfl_up(inc, s, 64);
        if (lane >= s) inc += t;
    }
    int off = inc - c;
    int deg = min(__shfl(inc, 63, 64), MAXDEG);
    {   // both waves write identical values — benign duplicate stores
        int o = off;
        unsigned mm = m0; int base = (2 * lane) * 32;
        while (mm) { int bit = __ffs(mm) - 1; mm &= mm - 1;
                     if (o < MAXDEG) lds[r][o] = base + bit; ++o; }
        mm = m1; base = (2 * lane + 1) * 32;
        while (mm) { int bit = __ffs(mm) - 1; mm &= mm - 1;
                     if (o < MAXDEG) lds[r][o] = base + bit; ++o; }
    }
    __syncthreads();
    int j0 = (lane < deg)      ? lds[r][lane]      : 0;
    int j1 = (lane + 64 < deg) ? lds[r][lane + 64] : 0;
    if (!half) {
        if (lane < deg)      nbr_c[i * MAXDEG + lane]      = j0;
        if (lane + 64 < deg) nbr_c[i * MAXDEG + lane + 64] = j1;
        if (lane == 0) deg_arr[i] = deg;
    }
    int h = (deg + 1) >> 1;
    float Z;
    float acc = agg_half(j0, j1, deg, sdin[i], ssin, hwin, lane,
                         half ? h : 0, half ? deg : h, &Z);
    if (half) accb[r][lane] = acc;
    __syncthreads();
    if (!half) {
        acc += accb[r][lane];
        float hv = fmaxf(acc / Z + b[lane], 0.f);
        float tr = transform_row(hv, W, lane);
        hwout[i * 64 + lane] = tr;
        float s1 = wave_reduce_sum(tr * asrc[lane]);
        float s2 = wave_reduce_sum(tr * adst[lane]);
        if (lane == 0) { ssout[i] = s1; sdout[i] = s2; }
    }
}

// ---- dispatch 3: layer-1 aggregate + relu + layer-2 transform + scores.
// 512-thr blocks, wave-pair per row (verified R4/R5/R8: absmax 0.0).
__global__ void __launch_bounds__(512, 8) agg_tr(
        const float* __restrict__ hwin, const float* __restrict__ ssin,
        const float* __restrict__ sdin, const int* __restrict__ nbr_c,
        const int* __restrict__ deg_arr, const float* __restrict__ b,
        const float* __restrict__ W, const float* __restrict__ asrc,
        const float* __restrict__ adst,
        float* __restrict__ hwout, float* __restrict__ ssout,
        float* __restrict__ sdout) {
    __shared__ float accb[4][64];
    int w    = threadIdx.x >> 6;      // 0..7
    int lane = threadIdx.x & 63;
    int r    = w >> 1;                // row slot 0..3
    int half = w & 1;
    int i = blockIdx.x * 4 + r;
    int deg = deg_arr[i];
    int j0 = (lane < deg)      ? nbr_c[i * MAXDEG + lane]      : 0;
    int j1 = (lane + 64 < deg) ? nbr_c[i * MAXDEG + lane + 64] : 0;
    int h  = (deg + 1) >> 1;
    float Z;
    float acc = agg_half(j0, j1, deg, sdin[i], ssin, hwin, lane,
                         half ? h : 0, half ? deg : h, &Z);
    if (half) accb[r][lane] = acc;
    __syncthreads();
    if (!half) {
        acc += accb[r][lane];
        float hv = fmaxf(acc / Z + b[lane], 0.f);
        float tr = transform_row(hv, W, lane);
        hwout[i * 64 + lane] = tr;
        float s1 = wave_reduce_sum(tr * asrc[lane]);
        float s2 = wave_reduce_sum(tr * adst[lane]);
        if (lane == 0) { ssout[i] = s1; sdout[i] = s2; }
    }
}

// ---- dispatch 4: layer-2 aggregate + residual + layernorm + val_w dot.
// ATOMIC-FREE finish (verified R8: -14.6 µs): plain per-block partial
// store; dispatch 5 reduces.
__global__ void __launch_bounds__(512, 8) agg_final(
        const float* __restrict__ hwin, const float* __restrict__ ssin,
        const float* __restrict__ sdin, const int* __restrict__ nbr_c,
        const int* __restrict__ deg_arr, const float* __restrict__ b,
        const float* __restrict__ x, const float* __restrict__ vw,
        float* __restrict__ partials) {
    __shared__ float accb[4][64];
    __shared__ float sp[4];
    int w    = threadIdx.x >> 6;
    int lane = threadIdx.x & 63;
    int r    = w >> 1;
    int half = w & 1;
    int i = blockIdx.x * 4 + r;
    int deg = deg_arr[i];
    int j0 = (lane < deg)      ? nbr_c[i * MAXDEG + lane]      : 0;
    int j1 = (lane + 64 < deg) ? nbr_c[i * MAXDEG + lane + 64] : 0;
    int h  = (deg + 1) >> 1;
    float Z;
    float acc = agg_half(j0, j1, deg, sdin[i], ssin, hwin, lane,
                         half ? h : 0, half ? deg : h, &Z);
    if (half) accb[r][lane] = acc;
    __syncthreads();
    if (!half) {
        acc += accb[r][lane];
        float hv = acc / Z + b[lane];
        float v  = x[i * 64 + lane] + hv;
        float mu = wave_reduce_sum(v) * (1.f / 64.f);
        float d  = v - mu;
        float var = wave_reduce_sum(d * d) * (1.f / 64.f);
        float ln  = d * rsqrtf(var + LN_EPS);
        float part = wave_reduce_sum(ln * vw[lane]);
        if (lane == 0) sp[r] = part;
    }
    __syncthreads();
    if (threadIdx.x == 0)
        partials[blockIdx.x] = sp[0] + sp[1] + sp[2] + sp[3];
}

// ---- dispatch 5: reduce 1024 block partials (fixed order) + relu.
__global__ void __launch_bounds__(256) finish_kernel(
        const float* __restrict__ partials, const float* __restrict__ vb,
        float* __restrict__ out) {
    __shared__ float sw[4];
    int lane = threadIdx.x & 63;
    int wave = threadIdx.x >> 6;
    float s = partials[threadIdx.x] + partials[threadIdx.x + 256]
            + partials[threadIdx.x + 512] + partials[threadIdx.x + 768];
    s = wave_reduce_sum(s);
    if (lane == 0) sw[wave] = s;
    __syncthreads();
    if (threadIdx.x == 0) {
        float t = sw[0] + sw[1] + sw[2] + sw[3];
        out[0] = fmaxf(t * (1.f / (float)N) + vb[0], 0.f);
    }
}

extern "C" void kernel_launch(void* const* d_in, const int* in_sizes, int n_in,
                              void* d_out, int out_size, void* d_ws, size_t ws_size,
                              hipStream_t stream) {
    const float4* adj4      = (const float4*)d_in[0];
    const int*   timestep   = (const int*)  d_in[1];
    const float* arrivals   = (const float*)d_in[2];
    const float* departures = (const float*)d_in[3];
    const float* hard       = (const float*)d_in[4];
    // d_in[5] active_agents: unused by reference
    const float* emb_w1     = (const float*)d_in[6];
    const float* emb_b1     = (const float*)d_in[7];
    const float* emb_w2     = (const float*)d_in[8];
    const float* emb_b2     = (const float*)d_in[9];
    const float* gat_w      = (const float*)d_in[10];
    const float* gat_asrc   = (const float*)d_in[11];
    const float* gat_adst   = (const float*)d_in[12];
    const float* gat_b      = (const float*)d_in[13];
    const float* val_w      = (const float*)d_in[14];
    const float* val_b      = (const float*)d_in[15];

    const size_t MB = 1u << 20;
    char* ws = (char*)d_ws;
    unsigned* bm   = (unsigned*)(ws);              // 2 MB (128 bands x 4096 cols)
    int*   nbr_c   = (int*)  (ws + 4 * MB);        // 2 MB
    int*   deg_arr = (int*)  (ws + 6 * MB);        // 16 KB
    float* x       = (float*)(ws + 7 * MB);        // 1 MB
    float* hwA     = (float*)(ws + 8 * MB);        // 1 MB
    float* hwB     = (float*)(ws + 9 * MB);        // 1 MB
    float* ssA     = (float*)(ws + 10 * MB);
    float* sdA     = (float*)(ws + 10 * MB + 65536);
    float* ssB     = (float*)(ws + 10 * MB + 131072);
    float* sdB     = (float*)(ws + 10 * MB + 196608);
    float* partials= (float*)(ws + 11 * MB);       // 4 KB (1024 floats)

    prep_kernel<<<1536, 256, 0, stream>>>(adj4, timestep, arrivals, departures, hard,
                                          emb_w1, emb_b1, emb_w2, emb_b2,
                                          gat_w, gat_asrc, gat_adst,
                                          (uint4*)bm, x, hwA, ssA, sdA);
    compact_agg_tr<<<N / 4, 512, 0, stream>>>(bm, hwA, ssA, sdA, gat_b,
                                              gat_w + 64 * 64, gat_asrc + 64,
                                              gat_adst + 64,
                                              nbr_c, deg_arr, hwB, ssB, sdB);
    agg_tr<<<N / 4, 512, 0, stream>>>(hwB, ssB, sdB, nbr_c, deg_arr, gat_b + 64,
                                      gat_w + 2 * 64 * 64, gat_asrc + 128,
                                      gat_adst + 128, hwA, ssA, sdA);
    agg_final<<<N / 4, 512, 0, stream>>>(hwA, ssA, sdA, nbr_c, deg_arr,
                                         gat_b + 128, x, val_w, partials);
    finish_kernel<<<1, 256, 0, stream>>>(partials, val_b, (float*)d_out);
    (void)in_sizes; (void)n_in; (void)out_size; (void)ws_size;
}